// Round 1
// 1578.178 us; speedup vs baseline: 1.2372x; 1.2372x over previous
//
#include <hip/hip_runtime.h>
#include <cstdint>
#include <cstddef>

typedef __bf16 bf16_t;
typedef __bf16 bf16x8 __attribute__((ext_vector_type(8)));
typedef float f32x4 __attribute__((ext_vector_type(4)));

#define B_  4
#define N_  64
#define FP_ 256
#define TP_ 32
#define V_  32000
#define D_  1024
#define L_  2048
#define M_  8192   // B_*L_

// -------- async global->LDS (16B per lane, wave-uniform LDS base) --------
__device__ __forceinline__ void async_copy16(const void* g, void* l) {
  __builtin_amdgcn_global_load_lds(
      (__attribute__((address_space(1))) void*)g,
      (__attribute__((address_space(3))) void*)l,
      16, 0, 0);
}

// -------- zero helper --------
__global__ void k_zero(float* __restrict__ p, int n) {
  int i = blockIdx.x * 256 + threadIdx.x;
  if (i < n) p[i] = 0.0f;
}

// -------- x_prime (B,N,FP,TP) fp32 -> Xb (M,FP) bf16, m = b*L + t*N + n --------
__global__ __launch_bounds__(256) void k_convert_x(const float* __restrict__ xp,
                                                   bf16_t* __restrict__ Xb) {
  __shared__ float tile[256][33];
  const int tid = threadIdx.x;
  const int b = blockIdx.x >> 6;
  const int n = blockIdx.x & 63;
  const float* src = xp + (size_t)(b * N_ + n) * FP_ * TP_;   // (f,t) 256x32
#pragma unroll
  for (int i = 0; i < 32; i++) {
    int idx = i * 256 + tid;
    tile[idx >> 5][idx & 31] = src[idx];
  }
  __syncthreads();
#pragma unroll
  for (int t = 0; t < 32; t++) {
    Xb[(size_t)(b * L_ + t * N_ + n) * FP_ + tid] = (bf16_t)tile[tid][t];
  }
}

// -------- transpose+convert: src (R,C) fp32 -> dst (C,R) bf16 --------
__global__ void k_transpose_cvt(const float* __restrict__ src, bf16_t* __restrict__ dst,
                                int R, int C) {
  __shared__ float tile[64][65];
  int ct = blockIdx.x;
  int rt = blockIdx.y;
  int tid = threadIdx.x;
#pragma unroll
  for (int i = 0; i < 16; i++) {
    int idx = tid + i * 256;
    int a = idx >> 6, bc = idx & 63;
    tile[a][bc] = src[(size_t)(rt * 64 + a) * C + ct * 64 + bc];
  }
  __syncthreads();
#pragma unroll
  for (int i = 0; i < 16; i++) {
    int idx = tid + i * 256;
    int a = idx >> 6, bc = idx & 63;
    dst[(size_t)(ct * 64 + a) * R + rt * 64 + bc] = (bf16_t)tile[bc][a];
  }
}

// ======== GEMM1: P[pr][v] = exp(X[m]·Wt[v] + bias[v]); rowsum[m] += sum_v ========
// New epilogue: stage exp() tile in LDS (reusing As/Bs) then 16B coalesced stores.
__global__ __launch_bounds__(256) void k_gemm1(
    const bf16_t* __restrict__ Xb, const bf16_t* __restrict__ Wt,
    const float* __restrict__ bias, bf16_t* __restrict__ P,
    float* __restrict__ rowsum, int mbase) {
  __shared__ __align__(16) bf16_t smem[128 * 128];   // 32 KB; K-loop: As|Bs, epilogue: Ct
  bf16_t* As = smem;
  bf16_t* Bs = smem + 128 * 64;

  const int tid = threadIdx.x;
  const int lane = tid & 63;
  const int wid = tid >> 6;
  const int wr = wid >> 1, wc = wid & 1;
  const int c16 = lane & 15, quad = lane >> 4;
  const int lrow = lane >> 3;
  const int lchunk = (lane & 7) ^ lrow;

  const int vtile = blockIdx.x;
  const int mtile = blockIdx.y;
  const int prow0 = mtile * 128;
  const int m0 = mbase + prow0;
  const int v0 = vtile * 128;

  f32x4 acc[4][4];
#pragma unroll
  for (int i = 0; i < 4; i++)
#pragma unroll
    for (int j = 0; j < 4; j++) acc[i][j] = (f32x4){0.f, 0.f, 0.f, 0.f};

  for (int kt = 0; kt < FP_; kt += 64) {
#pragma unroll
    for (int i = 0; i < 4; i++) {
      int r0 = (wid * 4 + i) * 8;
      int ra = r0 + lrow;
      async_copy16(Xb + (size_t)(m0 + ra) * FP_ + kt + lchunk * 8, &As[r0 * 64]);
      async_copy16(Wt + (size_t)(v0 + ra) * FP_ + kt + lchunk * 8, &Bs[r0 * 64]);
    }
    __syncthreads();
#pragma unroll
    for (int s = 0; s < 2; s++) {
      bf16x8 af[4], bfr[4];
      int g = s * 4 + quad;
#pragma unroll
      for (int i = 0; i < 4; i++) {
        int r = wr * 64 + i * 16 + c16;
        af[i] = *(const bf16x8*)&As[r * 64 + ((g ^ (r & 7)) << 3)];
        int rn = wc * 64 + i * 16 + c16;
        bfr[i] = *(const bf16x8*)&Bs[rn * 64 + ((g ^ (rn & 7)) << 3)];
      }
#pragma unroll
      for (int i = 0; i < 4; i++)
#pragma unroll
        for (int j = 0; j < 4; j++)
          acc[i][j] = __builtin_amdgcn_mfma_f32_16x16x32_bf16(af[i], bfr[j], acc[i][j], 0, 0, 0);
    }
    __syncthreads();
  }

  float bv[4];
#pragma unroll
  for (int j = 0; j < 4; j++) bv[j] = bias[v0 + wc * 64 + j * 16 + c16];

  // exp + rowsum + stage bf16 tile into LDS (swizzled by row&7 to spread banks)
#pragma unroll
  for (int i = 0; i < 4; i++) {
#pragma unroll
    for (int e = 0; e < 4; e++) {
      int rl = wr * 64 + i * 16 + quad * 4 + e;
      float s = 0.0f;
#pragma unroll
      for (int j = 0; j < 4; j++) {
        float p = __expf(acc[i][j][e] + bv[j]);
        bf16_t pb = (bf16_t)p;
        int ch = wc * 8 + j * 2 + (c16 >> 3);
        smem[rl * 128 + ((ch ^ (rl & 7)) << 3) + (c16 & 7)] = pb;
        s += (float)pb;
      }
#pragma unroll
      for (int off = 1; off < 16; off <<= 1) s += __shfl_xor(s, off, 16);
      if (c16 == 0) atomicAdd(&rowsum[m0 + rl], s);
    }
  }
  __syncthreads();
  // coalesced vectorized store: 8 x b128 per thread (was 16 scalar 2B stores)
#pragma unroll
  for (int it = 0; it < 8; it++) {
    int idx = it * 256 + tid;
    int row = idx >> 4;
    int ch = idx & 15;
    *(bf16x8*)&P[(size_t)(prow0 + row) * V_ + v0 + ch * 8] =
        *(const bf16x8*)&smem[row * 128 + ((ch ^ (row & 7)) << 3)];
  }
}

// ======== GEMM2: partial[ks][pr][d] = sum_{v in slice} P[pr][v]*Et[d][v] ========
// 256x256 tile, BK=32, 8 waves (2m x 4n, wave tile 128x64), 3-buffer LDS ring,
// counted vmcnt(4) pipeline (prefetch t+2 while computing t), setprio, XCD swizzle.
__global__ __launch_bounds__(512, 2) void k_gemm2(
    const bf16_t* __restrict__ P, const bf16_t* __restrict__ Et,
    float* __restrict__ partial, int mtiles, int chunkrows, int kper) {
  __shared__ __align__(16) bf16_t lds[3][16384];   // 96 KB: per buf A 256x32 | B 256x32

  const int tid = threadIdx.x;
  const int lane = tid & 63;
  const int wid = tid >> 6;          // 0..7
  const int wm = wid >> 2;           // 0..1
  const int wn = wid & 3;            // 0..3
  const int c16 = lane & 15, quad = lane >> 4;

  // XCD-chunked bijective swizzle (nwg % 8 == 0 always: nwg = 4*mt*ks, ks even)
  const int nwg = (int)gridDim.x;
  const int xcd = blockIdx.x & 7;
  const int vb = xcd * (nwg >> 3) + ((int)blockIdx.x >> 3);
  const int dtile = vb & 3;
  const int rest = vb >> 2;
  const int mtile = rest % mtiles;
  const int kslice = rest / mtiles;

  const int d0 = dtile * 256;
  const int prow0 = mtile * 256;          // chunk-local P row
  const int kbase = kslice * kper;
  float* __restrict__ o = partial + (size_t)kslice * chunkrows * D_;

  // staging geometry: 16-row x 32-col window per wave-load; pair-of-rows XOR swizzle
  const int l3 = lane >> 3;
  const int cA = (lane & 7) ^ l3;
  const int grA = (l3 << 1) + (cA >> 2);   // row offset in window
  const int gcA = (cA & 3) << 3;           // elem offset in 32-wide K

  const bf16_t* srcA0 = P  + (size_t)(prow0 + (wid * 2 + 0) * 16 + grA) * V_ + kbase + gcA;
  const bf16_t* srcA1 = P  + (size_t)(prow0 + (wid * 2 + 1) * 16 + grA) * V_ + kbase + gcA;
  const bf16_t* srcB0 = Et + (size_t)(d0   + (wid * 2 + 0) * 16 + grA) * V_ + kbase + gcA;
  const bf16_t* srcB1 = Et + (size_t)(d0   + (wid * 2 + 1) * 16 + grA) * V_ + kbase + gcA;
  const int ldsOfs0 = (wid * 2 + 0) * 16 * 32;   // wave-uniform LDS elem offsets
  const int ldsOfs1 = (wid * 2 + 1) * 16 * 32;

  f32x4 acc[8][4];
#pragma unroll
  for (int i = 0; i < 8; i++)
#pragma unroll
    for (int j = 0; j < 4; j++) acc[i][j] = (f32x4){0.f, 0.f, 0.f, 0.f};

  const int NT = kper >> 5;   // K-tiles of 32

  // prologue: stage tiles 0,1 into bufs 0,1 (4 loads/thread/tile)
#pragma unroll
  for (int t = 0; t < 2; t++) {
    bf16_t* As = &lds[t][0];
    bf16_t* Bs = &lds[t][8192];
    async_copy16(srcA0 + t * 32, &As[ldsOfs0]);
    async_copy16(srcA1 + t * 32, &As[ldsOfs1]);
    async_copy16(srcB0 + t * 32, &Bs[ldsOfs0]);
    async_copy16(srcB1 + t * 32, &Bs[ldsOfs1]);
  }

  int cur = 0;
  for (int t = 0; t < NT; ++t) {
    // counted wait: tile t landed (tile t+1's 4 loads may stay in flight). Never
    // drain in-loop (T4). Per-wave wait + barrier => all waves' DMAs for buf cur done.
    if (t < NT - 1) asm volatile("s_waitcnt vmcnt(4)" ::: "memory");
    else            asm volatile("s_waitcnt vmcnt(0)" ::: "memory");
    asm volatile("s_barrier" ::: "memory");

    // prefetch tile t+2 into the ring slot freed at the barrier above
    const int nx2 = (cur == 0) ? 2 : cur - 1;
    if (t < NT - 2) {
      bf16_t* As2 = &lds[nx2][0];
      bf16_t* Bs2 = &lds[nx2][8192];
      const size_t ko = (size_t)(t + 2) * 32;
      async_copy16(srcA0 + ko, &As2[ldsOfs0]);
      async_copy16(srcA1 + ko, &As2[ldsOfs1]);
      async_copy16(srcB0 + ko, &Bs2[ldsOfs0]);
      async_copy16(srcB1 + ko, &Bs2[ldsOfs1]);
    }

    const bf16_t* As = &lds[cur][0];
    const bf16_t* Bs = &lds[cur][8192];

    bf16x8 bfr[4];
#pragma unroll
    for (int j = 0; j < 4; j++) {
      int rn = wn * 64 + j * 16 + c16;
      int pn = rn >> 1;
      int cz = (((rn & 1) << 2) | quad) ^ (pn & 7);
      bfr[j] = *(const bf16x8*)&Bs[pn * 64 + (cz << 3)];
    }
    __builtin_amdgcn_s_setprio(1);
#pragma unroll
    for (int i = 0; i < 8; i++) {
      int r = wm * 128 + i * 16 + c16;
      int pa = r >> 1;
      int cz = (((r & 1) << 2) | quad) ^ (pa & 7);
      bf16x8 a = *(const bf16x8*)&As[pa * 64 + (cz << 3)];
#pragma unroll
      for (int j = 0; j < 4; j++)
        acc[i][j] = __builtin_amdgcn_mfma_f32_16x16x32_bf16(a, bfr[j], acc[i][j], 0, 0, 0);
    }
    __builtin_amdgcn_s_setprio(0);
    cur = (cur == 2) ? 0 : cur + 1;
  }

  // epilogue: plain fp32 stores into this k-slice's partial (no atomics)
#pragma unroll
  for (int i = 0; i < 8; i++) {
#pragma unroll
    for (int e = 0; e < 4; e++) {
      int pr = prow0 + wm * 128 + i * 16 + quad * 4 + e;
#pragma unroll
      for (int j = 0; j < 4; j++) {
        int d = d0 + wn * 64 + j * 16 + c16;
        o[(size_t)pr * D_ + d] = acc[i][j][e];
      }
    }
  }
}

// -------- finalize: out[mbase+lr][:] = (sum_z partial[z]) / rowsum --------
__global__ void k_finalize(const float* __restrict__ partial,
                           const float* __restrict__ rowsum, float* __restrict__ out,
                           int mbase, int rows, int ks) {
  int i = blockIdx.x * 256 + threadIdx.x;   // over rows*D/4
  int lr = i >> 8;                          // /(D_/4)
  float inv = 1.0f / rowsum[mbase + lr];
  f32x4 s = (f32x4){0.f, 0.f, 0.f, 0.f};
  for (int z = 0; z < ks; z++) {
    f32x4 a = ((const f32x4*)(partial + (size_t)z * rows * D_))[i];
    s.x += a.x; s.y += a.y; s.z += a.z; s.w += a.w;
  }
  s.x *= inv; s.y *= inv; s.z *= inv; s.w *= inv;
  ((f32x4*)out)[(size_t)mbase * (D_ / 4) + i] = s;
}

// ======== host ========
extern "C" void kernel_launch(void* const* d_in, const int* in_sizes, int n_in,
                              void* d_out, int out_size, void* d_ws, size_t ws_size,
                              hipStream_t stream) {
  const float* xp   = (const float*)d_in[0];   // (B,N,FP,TP)
  const float* E    = (const float*)d_in[1];   // (V,D)
  const float* W    = (const float*)d_in[2];   // (FP,V)
  const float* bias = (const float*)d_in[3];   // (V)
  float* out = (float*)d_out;                  // (M,D)

  char* ws = (char*)d_ws;
  const size_t szXb = (size_t)M_ * FP_ * 2;
  const size_t szWt = (size_t)V_ * FP_ * 2;
  const size_t szEt = (size_t)D_ * V_ * 2;
  const size_t szRs = (size_t)M_ * 4;
  bf16_t* Xb = (bf16_t*)ws;
  bf16_t* Wt = (bf16_t*)(ws + szXb);
  bf16_t* Et = (bf16_t*)(ws + szXb + szWt);
  float* rowsum = (float*)(ws + szXb + szWt + szEt);
  const size_t fixed = szXb + szWt + szEt + szRs;

  // chunk rows so that P-chunk (V*2 B/row) + worst-case partials (ks<=8: 8*D*4 B/row) fit
  size_t avail = (ws_size > fixed) ? ws_size - fixed : 0;
  long cr = (long)(avail / ((size_t)V_ * 2 + (size_t)8 * D_ * 4));   // 96768 B/row
  cr = (cr / 256) * 256;
  if (cr > M_) cr = M_;
  if (cr < 256) cr = 256;
  const int chunk = (int)cr;
  bf16_t* P = (bf16_t*)(ws + fixed);
  float* partial = (float*)(ws + fixed + (size_t)chunk * V_ * 2);

  k_zero<<<(M_ + 255) / 256, 256, 0, stream>>>(rowsum, M_);
  k_convert_x<<<B_ * N_, 256, 0, stream>>>(xp, Xb);
  {
    dim3 g(V_ / 64, FP_ / 64);
    k_transpose_cvt<<<g, 256, 0, stream>>>(W, Wt, FP_, V_);
  }
  {
    dim3 g(D_ / 64, V_ / 64);
    k_transpose_cvt<<<g, 256, 0, stream>>>(E, Et, V_, D_);
  }

  for (int mb = 0; mb < M_; mb += chunk) {
    int rows = M_ - mb;
    if (rows > chunk) rows = chunk;
    dim3 g1(V_ / 128, rows / 128);
    k_gemm1<<<g1, 256, 0, stream>>>(Xb, Wt, bias, P, rowsum, mb);

    int mt = rows / 256;
    int ks = (mt >= 32) ? 2 : (mt >= 16 ? 4 : 8);   // fill >=256 CUs; V_/ks % 32 == 0
    int kper = V_ / ks;
    int nwg = 4 * mt * ks;
    k_gemm2<<<nwg, 512, 0, stream>>>(P, Et, partial, mt, rows, kper);

    k_finalize<<<rows, 256, 0, stream>>>(partial, rowsum, out, mb, rows, ks);
  }
}

// Round 2
// 1481.649 us; speedup vs baseline: 1.3178x; 1.0651x over previous
//
#include <hip/hip_runtime.h>
#include <cstdint>
#include <cstddef>

typedef __bf16 bf16_t;
typedef __bf16 bf16x8 __attribute__((ext_vector_type(8)));
typedef float f32x4 __attribute__((ext_vector_type(4)));

#define B_  4
#define N_  64
#define FP_ 256
#define TP_ 32
#define V_  32000
#define D_  1024
#define L_  2048
#define M_  8192   // B_*L_

// -------- async global->LDS (16B per lane, wave-uniform LDS base) --------
__device__ __forceinline__ void async_copy16(const void* g, void* l) {
  __builtin_amdgcn_global_load_lds(
      (__attribute__((address_space(1))) void*)g,
      (__attribute__((address_space(3))) void*)l,
      16, 0, 0);
}

// -------- zero helper --------
__global__ void k_zero(float* __restrict__ p, int n) {
  int i = blockIdx.x * 256 + threadIdx.x;
  if (i < n) p[i] = 0.0f;
}

// -------- x_prime (B,N,FP,TP) fp32 -> Xb (M,FP) bf16, m = b*L + t*N + n --------
__global__ __launch_bounds__(256) void k_convert_x(const float* __restrict__ xp,
                                                   bf16_t* __restrict__ Xb) {
  __shared__ float tile[256][33];
  const int tid = threadIdx.x;
  const int b = blockIdx.x >> 6;
  const int n = blockIdx.x & 63;
  const float* src = xp + (size_t)(b * N_ + n) * FP_ * TP_;   // (f,t) 256x32
#pragma unroll
  for (int i = 0; i < 32; i++) {
    int idx = i * 256 + tid;
    tile[idx >> 5][idx & 31] = src[idx];
  }
  __syncthreads();
#pragma unroll
  for (int t = 0; t < 32; t++) {
    Xb[(size_t)(b * L_ + t * N_ + n) * FP_ + tid] = (bf16_t)tile[tid][t];
  }
}

// -------- transpose+convert: src (R,C) fp32 -> dst (C,R) bf16 --------
__global__ void k_transpose_cvt(const float* __restrict__ src, bf16_t* __restrict__ dst,
                                int R, int C) {
  __shared__ float tile[64][65];
  int ct = blockIdx.x;
  int rt = blockIdx.y;
  int tid = threadIdx.x;
#pragma unroll
  for (int i = 0; i < 16; i++) {
    int idx = tid + i * 256;
    int a = idx >> 6, bc = idx & 63;
    tile[a][bc] = src[(size_t)(rt * 64 + a) * C + ct * 64 + bc];
  }
  __syncthreads();
#pragma unroll
  for (int i = 0; i < 16; i++) {
    int idx = tid + i * 256;
    int a = idx >> 6, bc = idx & 63;
    dst[(size_t)(ct * 64 + a) * R + rt * 64 + bc] = (bf16_t)tile[bc][a];
  }
}

// ======== GEMM1: P[pr][v] = exp(X[m]·Wt[v] + bias[v]); rowsum[m] += sum_v ========
__global__ __launch_bounds__(256) void k_gemm1(
    const bf16_t* __restrict__ Xb, const bf16_t* __restrict__ Wt,
    const float* __restrict__ bias, bf16_t* __restrict__ P,
    float* __restrict__ rowsum, int mbase) {
  __shared__ __align__(16) bf16_t smem[128 * 128];   // 32 KB; K-loop: As|Bs, epilogue: Ct
  bf16_t* As = smem;
  bf16_t* Bs = smem + 128 * 64;

  const int tid = threadIdx.x;
  const int lane = tid & 63;
  const int wid = tid >> 6;
  const int wr = wid >> 1, wc = wid & 1;
  const int c16 = lane & 15, quad = lane >> 4;
  const int lrow = lane >> 3;
  const int lchunk = (lane & 7) ^ lrow;

  const int vtile = blockIdx.x;
  const int mtile = blockIdx.y;
  const int prow0 = mtile * 128;
  const int m0 = mbase + prow0;
  const int v0 = vtile * 128;

  f32x4 acc[4][4];
#pragma unroll
  for (int i = 0; i < 4; i++)
#pragma unroll
    for (int j = 0; j < 4; j++) acc[i][j] = (f32x4){0.f, 0.f, 0.f, 0.f};

  for (int kt = 0; kt < FP_; kt += 64) {
#pragma unroll
    for (int i = 0; i < 4; i++) {
      int r0 = (wid * 4 + i) * 8;
      int ra = r0 + lrow;
      async_copy16(Xb + (size_t)(m0 + ra) * FP_ + kt + lchunk * 8, &As[r0 * 64]);
      async_copy16(Wt + (size_t)(v0 + ra) * FP_ + kt + lchunk * 8, &Bs[r0 * 64]);
    }
    __syncthreads();
#pragma unroll
    for (int s = 0; s < 2; s++) {
      bf16x8 af[4], bfr[4];
      int g = s * 4 + quad;
#pragma unroll
      for (int i = 0; i < 4; i++) {
        int r = wr * 64 + i * 16 + c16;
        af[i] = *(const bf16x8*)&As[r * 64 + ((g ^ (r & 7)) << 3)];
        int rn = wc * 64 + i * 16 + c16;
        bfr[i] = *(const bf16x8*)&Bs[rn * 64 + ((g ^ (rn & 7)) << 3)];
      }
#pragma unroll
      for (int i = 0; i < 4; i++)
#pragma unroll
        for (int j = 0; j < 4; j++)
          acc[i][j] = __builtin_amdgcn_mfma_f32_16x16x32_bf16(af[i], bfr[j], acc[i][j], 0, 0, 0);
    }
    __syncthreads();
  }

  float bv[4];
#pragma unroll
  for (int j = 0; j < 4; j++) bv[j] = bias[v0 + wc * 64 + j * 16 + c16];

#pragma unroll
  for (int i = 0; i < 4; i++) {
#pragma unroll
    for (int e = 0; e < 4; e++) {
      int rl = wr * 64 + i * 16 + quad * 4 + e;
      float s = 0.0f;
#pragma unroll
      for (int j = 0; j < 4; j++) {
        float p = __expf(acc[i][j][e] + bv[j]);
        bf16_t pb = (bf16_t)p;
        int ch = wc * 8 + j * 2 + (c16 >> 3);
        smem[rl * 128 + ((ch ^ (rl & 7)) << 3) + (c16 & 7)] = pb;
        s += (float)pb;
      }
#pragma unroll
      for (int off = 1; off < 16; off <<= 1) s += __shfl_xor(s, off, 16);
      if (c16 == 0) atomicAdd(&rowsum[m0 + rl], s);
    }
  }
  __syncthreads();
#pragma unroll
  for (int it = 0; it < 8; it++) {
    int idx = it * 256 + tid;
    int row = idx >> 4;
    int ch = idx & 15;
    *(bf16x8*)&P[(size_t)(prow0 + row) * V_ + v0 + ch * 8] =
        *(const bf16x8*)&smem[row * 128 + ((ch ^ (row & 7)) << 3)];
  }
}

// ======== GEMM2: 256x256 tile, BK=64 (2x K32 subtiles), 8 waves (2m x 4n),
// 2-buffer LDS (128 KB), 4 phases per K-tile, counted vmcnt gates (never drain),
// setprio around each 16-MFMA cluster, XCD-chunked block swizzle.
// Phase order (mh,nh): (0,0),(0,1),(1,1),(1,0); stage order: Aa,Ba,Bb,Ab.
// Gate derivation (per-thread loads, 2 per stage): every steady gate = vmcnt(4).
__global__ __launch_bounds__(512, 2) void k_gemm2(
    const bf16_t* __restrict__ P, const bf16_t* __restrict__ Et,
    float* __restrict__ partial, int mtiles, int chunkrows, int kper) {
  __shared__ __align__(16) bf16_t ldsA[2][2][8192];   // [buf][kk][256 rows x 32 cols, pair-row form]
  __shared__ __align__(16) bf16_t ldsB[2][2][8192];

  const int tid = threadIdx.x;
  const int lane = tid & 63;
  const int wid = tid >> 6;          // 0..7
  const int wm = wid >> 2;           // 0..1
  const int wn = wid & 3;            // 0..3
  const int c16 = lane & 15, quad = lane >> 4;

  // XCD-chunked bijective swizzle (nwg % 8 == 0 by construction)
  const int nwg = (int)gridDim.x;
  const int xcd = blockIdx.x & 7;
  const int vb = xcd * (nwg >> 3) + ((int)blockIdx.x >> 3);
  const int dtile = vb & 3;
  const int rest = vb >> 2;
  const int mtile = rest % mtiles;
  const int kslice = rest / mtiles;

  const int d0 = dtile * 256;
  const int prow0 = mtile * 256;
  const int kbase = kslice * kper;
  float* __restrict__ o = partial + (size_t)kslice * chunkrows * D_;

  // staging lane geometry (proven conflict-free stage/read swizzle pair)
  const int l3 = lane >> 3;
  const int cA = (lane & 7) ^ l3;
  const int grA = (l3 << 1) + (cA >> 2);
  const int gcA = (cA & 3) << 3;

  const int rA0 = (wid & 4) * 32 + (wid & 3) * 16;   // A half-a rows {0-63,128-191}
  const int rB0 = (wid >> 1) * 64 + (wid & 1) * 16;  // B half-a rows {0-31,64-95,128-159,192-223}

  const bf16_t* gA = P  + (size_t)(prow0 + grA) * V_ + kbase + gcA;
  const bf16_t* gB = Et + (size_t)(d0   + grA) * V_ + kbase + gcA;

  f32x4 acc[8][4];
#pragma unroll
  for (int i = 0; i < 8; i++)
#pragma unroll
    for (int j = 0; j < 4; j++) acc[i][j] = (f32x4){0.f, 0.f, 0.f, 0.f};

  bf16x8 af[4][2], bfr[2][2];

#define STAGE_A(buf, t, half)                                          \
  do {                                                                 \
    int r0_ = rA0 + (half) * 64;                                       \
    const bf16_t* s_ = gA + (size_t)r0_ * V_ + (t) * 64;               \
    async_copy16(s_,      &ldsA[buf][0][r0_ * 32]);                    \
    async_copy16(s_ + 32, &ldsA[buf][1][r0_ * 32]);                    \
  } while (0)
#define STAGE_B(buf, t, half)                                          \
  do {                                                                 \
    int r0_ = rB0 + (half) * 32;                                       \
    const bf16_t* s_ = gB + (size_t)r0_ * V_ + (t) * 64;               \
    async_copy16(s_,      &ldsB[buf][0][r0_ * 32]);                    \
    async_copy16(s_ + 32, &ldsB[buf][1][r0_ * 32]);                    \
  } while (0)
#define READ_A(buf, mh)                                                \
  do {                                                                 \
    _Pragma("unroll")                                                  \
    for (int i_ = 0; i_ < 4; i_++) {                                   \
      int r_ = wm * 128 + (mh) * 64 + i_ * 16 + c16;                   \
      int pa_ = r_ >> 1;                                               \
      int cz_ = ((((r_ & 1) << 2) | quad) ^ (pa_ & 7)) << 3;           \
      af[i_][0] = *(const bf16x8*)&ldsA[buf][0][pa_ * 64 + cz_];       \
      af[i_][1] = *(const bf16x8*)&ldsA[buf][1][pa_ * 64 + cz_];       \
    }                                                                  \
  } while (0)
#define READ_B(buf, nh)                                                \
  do {                                                                 \
    _Pragma("unroll")                                                  \
    for (int j_ = 0; j_ < 2; j_++) {                                   \
      int r_ = wn * 64 + (nh) * 32 + j_ * 16 + c16;                    \
      int pn_ = r_ >> 1;                                               \
      int cz_ = ((((r_ & 1) << 2) | quad) ^ (pn_ & 7)) << 3;           \
      bfr[j_][0] = *(const bf16x8*)&ldsB[buf][0][pn_ * 64 + cz_];      \
      bfr[j_][1] = *(const bf16x8*)&ldsB[buf][1][pn_ * 64 + cz_];      \
    }                                                                  \
  } while (0)
#define MFMA16(mh, nh)                                                 \
  do {                                                                 \
    __builtin_amdgcn_s_setprio(1);                                     \
    _Pragma("unroll")                                                  \
    for (int i_ = 0; i_ < 4; i_++)                                     \
      _Pragma("unroll")                                                \
      for (int j_ = 0; j_ < 2; j_++) {                                 \
        acc[(mh)*4 + i_][(nh)*2 + j_] = __builtin_amdgcn_mfma_f32_16x16x32_bf16( \
            af[i_][0], bfr[j_][0], acc[(mh)*4 + i_][(nh)*2 + j_], 0, 0, 0);      \
        acc[(mh)*4 + i_][(nh)*2 + j_] = __builtin_amdgcn_mfma_f32_16x16x32_bf16( \
            af[i_][1], bfr[j_][1], acc[(mh)*4 + i_][(nh)*2 + j_], 0, 0, 0);      \
      }                                                                \
    __builtin_amdgcn_s_setprio(0);                                     \
  } while (0)
#define BAR() asm volatile("s_barrier" ::: "memory")
#define VMW(n) asm volatile("s_waitcnt vmcnt(" #n ")" ::: "memory")
#define LGW(n) asm volatile("s_waitcnt lgkmcnt(" #n ")" ::: "memory")

  // prologue: stage tile 0 in consumption-aligned order; gate p0 needs Aa,Ba -> allow 4
  STAGE_A(0, 0, 0); STAGE_B(0, 0, 0); STAGE_B(0, 0, 1); STAGE_A(0, 0, 1);
  VMW(4);
  BAR();

  const int NT = kper >> 6;
  for (int t = 0; t < NT; ++t) {
    const int cur = t & 1, nb = cur ^ 1;
    const bool pf = (t + 1 < NT);

    // ---- p0: (mh0, nh0) ---- needs Aa(t), Ba(t)
    READ_A(cur, 0); READ_B(cur, 0);
    if (pf) STAGE_A(nb, t + 1, 0);
    LGW(8);
    BAR();
    LGW(0);
    MFMA16(0, 0);
    if (pf) VMW(4); else VMW(2);     // gate p1: needs Bb(t)
    BAR();

    // ---- p1: (mh0, nh1) ---- needs Bb(t)
    READ_B(cur, 1);
    if (pf) STAGE_B(nb, t + 1, 0);
    BAR();
    LGW(0);
    MFMA16(0, 1);
    if (pf) VMW(4); else VMW(0);     // gate p2: needs Ab(t)
    BAR();

    // ---- p2: (mh1, nh1) ---- needs Ab(t)
    READ_A(cur, 1);
    if (pf) STAGE_B(nb, t + 1, 1);
    BAR();
    LGW(0);
    MFMA16(1, 1);
    BAR();                           // p3 re-reads Ba(t): already resident

    // ---- p3: (mh1, nh0) ----
    READ_B(cur, 0);
    if (pf) STAGE_A(nb, t + 1, 1);
    BAR();
    LGW(0);
    MFMA16(1, 0);
    if (pf) {                        // gate next-tile p0: needs Aa(t+1), Ba(t+1)
      VMW(4);
      BAR();
    }
  }

  // epilogue: plain fp32 stores; acc[I][J]: row = wm*128 + (I>>2)*64 + (I&3)*16,
  // col = wn*64 + (J>>1)*32 + (J&1)*16
#pragma unroll
  for (int I = 0; I < 8; I++) {
    int rowb = wm * 128 + (I >> 2) * 64 + (I & 3) * 16;
#pragma unroll
    for (int e = 0; e < 4; e++) {
      int pr = prow0 + rowb + quad * 4 + e;
#pragma unroll
      for (int J = 0; J < 4; J++) {
        int d = d0 + wn * 64 + (J >> 1) * 32 + (J & 1) * 16 + c16;
        o[(size_t)pr * D_ + d] = acc[I][J][e];
      }
    }
  }
#undef STAGE_A
#undef STAGE_B
#undef READ_A
#undef READ_B
#undef MFMA16
#undef BAR
#undef VMW
#undef LGW
}

// -------- finalize: out[mbase+lr][:] = (sum_z partial[z]) / rowsum --------
__global__ void k_finalize(const float* __restrict__ partial,
                           const float* __restrict__ rowsum, float* __restrict__ out,
                           int mbase, int rows, int ks) {
  int i = blockIdx.x * 256 + threadIdx.x;   // over rows*D/4
  int lr = i >> 8;                          // /(D_/4)
  float inv = 1.0f / rowsum[mbase + lr];
  f32x4 s = (f32x4){0.f, 0.f, 0.f, 0.f};
  for (int z = 0; z < ks; z++) {
    f32x4 a = ((const f32x4*)(partial + (size_t)z * rows * D_))[i];
    s.x += a.x; s.y += a.y; s.z += a.z; s.w += a.w;
  }
  s.x *= inv; s.y *= inv; s.z *= inv; s.w *= inv;
  ((f32x4*)out)[(size_t)mbase * (D_ / 4) + i] = s;
}

// ======== host ========
extern "C" void kernel_launch(void* const* d_in, const int* in_sizes, int n_in,
                              void* d_out, int out_size, void* d_ws, size_t ws_size,
                              hipStream_t stream) {
  const float* xp   = (const float*)d_in[0];   // (B,N,FP,TP)
  const float* E    = (const float*)d_in[1];   // (V,D)
  const float* W    = (const float*)d_in[2];   // (FP,V)
  const float* bias = (const float*)d_in[3];   // (V)
  float* out = (float*)d_out;                  // (M,D)

  char* ws = (char*)d_ws;
  const size_t szXb = (size_t)M_ * FP_ * 2;
  const size_t szWt = (size_t)V_ * FP_ * 2;
  const size_t szEt = (size_t)D_ * V_ * 2;
  const size_t szRs = (size_t)M_ * 4;
  bf16_t* Xb = (bf16_t*)ws;
  bf16_t* Wt = (bf16_t*)(ws + szXb);
  bf16_t* Et = (bf16_t*)(ws + szXb + szWt);
  float* rowsum = (float*)(ws + szXb + szWt + szEt);
  const size_t fixed = szXb + szWt + szEt + szRs;

  // chunk from {8192,4096,2048,1024} (keeps nwg = 4*mt*ks at 256 or 320, grid fills
  // whole CU rounds); ks chosen so kper = V/ks is divisible by 64.
  const int copt[4] = {8192, 4096, 2048, 1024};
  const int kopt[4] = {2, 4, 10, 20};
  int chunk = 1024, ksv = 20;
  size_t avail = (ws_size > fixed) ? ws_size - fixed : 0;
  for (int i = 0; i < 4; i++) {
    size_t need = (size_t)copt[i] * V_ * 2 + (size_t)kopt[i] * copt[i] * D_ * 4;
    if (need <= avail) { chunk = copt[i]; ksv = kopt[i]; break; }
  }
  bf16_t* P = (bf16_t*)(ws + fixed);
  float* partial = (float*)(ws + fixed + (size_t)chunk * V_ * 2);
  const int kper = V_ / ksv;

  k_zero<<<(M_ + 255) / 256, 256, 0, stream>>>(rowsum, M_);
  k_convert_x<<<B_ * N_, 256, 0, stream>>>(xp, Xb);
  {
    dim3 g(V_ / 64, FP_ / 64);
    k_transpose_cvt<<<g, 256, 0, stream>>>(W, Wt, FP_, V_);
  }
  {
    dim3 g(D_ / 64, V_ / 64);
    k_transpose_cvt<<<g, 256, 0, stream>>>(E, Et, V_, D_);
  }

  for (int mb = 0; mb < M_; mb += chunk) {
    int rows = M_ - mb;
    if (rows > chunk) rows = chunk;          // always == chunk (M_ % chunk == 0)
    dim3 g1(V_ / 128, rows / 128);
    k_gemm1<<<g1, 256, 0, stream>>>(Xb, Wt, bias, P, rowsum, mb);

    int mt = rows / 256;
    int nwg = 4 * mt * ksv;
    k_gemm2<<<nwg, 512, 0, stream>>>(P, Et, partial, mt, rows, kper);

    k_finalize<<<rows, 256, 0, stream>>>(partial, rowsum, out, mb, rows, ksv);
  }
}

// Round 4
// 1180.552 us; speedup vs baseline: 1.6539x; 1.2550x over previous
//
#include <hip/hip_runtime.h>
#include <cstdint>
#include <cstddef>

typedef __bf16 bf16_t;
typedef __bf16 bf16x8 __attribute__((ext_vector_type(8)));
typedef float f32x4 __attribute__((ext_vector_type(4)));

#define B_  4
#define N_  64
#define FP_ 256
#define TP_ 32
#define V_  32000
#define D_  1024
#define L_  2048
#define M_  8192   // B_*L_
#define VT_ 125    // V_/256

// -------- async global->LDS (16B per lane, wave-uniform LDS base) --------
__device__ __forceinline__ void async_copy16(const void* g, void* l) {
  __builtin_amdgcn_global_load_lds(
      (__attribute__((address_space(1))) void*)g,
      (__attribute__((address_space(3))) void*)l,
      16, 0, 0);
}

// -------- x_prime (B,N,FP,TP) fp32 -> Xb (M,FP) bf16, m = b*L + t*N + n --------
__global__ __launch_bounds__(256) void k_convert_x(const float* __restrict__ xp,
                                                   bf16_t* __restrict__ Xb) {
  __shared__ float tile[256][33];
  const int tid = threadIdx.x;
  const int b = blockIdx.x >> 6;
  const int n = blockIdx.x & 63;
  const float* src = xp + (size_t)(b * N_ + n) * FP_ * TP_;   // (f,t) 256x32
#pragma unroll
  for (int i = 0; i < 32; i++) {
    int idx = i * 256 + tid;
    tile[idx >> 5][idx & 31] = src[idx];
  }
  __syncthreads();
#pragma unroll
  for (int t = 0; t < 32; t++) {
    Xb[(size_t)(b * L_ + t * N_ + n) * FP_ + tid] = (bf16_t)tile[tid][t];
  }
}

// -------- transpose+convert: src (R,C) fp32 -> dst (C,R) bf16 --------
__global__ void k_transpose_cvt(const float* __restrict__ src, bf16_t* __restrict__ dst,
                                int R, int C) {
  __shared__ float tile[64][65];
  int ct = blockIdx.x;
  int rt = blockIdx.y;
  int tid = threadIdx.x;
#pragma unroll
  for (int i = 0; i < 16; i++) {
    int idx = tid + i * 256;
    int a = idx >> 6, bc = idx & 63;
    tile[a][bc] = src[(size_t)(rt * 64 + a) * C + ct * 64 + bc];
  }
  __syncthreads();
#pragma unroll
  for (int i = 0; i < 16; i++) {
    int idx = tid + i * 256;
    int a = idx >> 6, bc = idx & 63;
    dst[(size_t)(ct * 64 + a) * R + rt * 64 + bc] = (bf16_t)tile[bc][a];
  }
}

#define BAR() asm volatile("s_barrier" ::: "memory")
#define VMW(n) asm volatile("s_waitcnt vmcnt(" #n ")" ::: "memory")
#define LGW(n) asm volatile("s_waitcnt lgkmcnt(" #n ")" ::: "memory")

// ======== GEMM1: P[pr][v] = exp(X[m]·Wt[v] + bias[v]) ========
// rs_part[pr][vtile*4 + wn] = per-wave 64-col partial sum (one slot PER WAVE —
// four waves cover each row; round-3 bug was racing them into one slot).
__global__ __launch_bounds__(512, 2) void k_gemm1(
    const bf16_t* __restrict__ Xb, const bf16_t* __restrict__ Wt,
    const float* __restrict__ bias, bf16_t* __restrict__ P,
    float* __restrict__ rs_part, int mbase) {
  __shared__ __align__(16) bf16_t smem[65536];   // 128 KB: A 64K | B 64K ; epilogue 256x256

  const int tid = threadIdx.x;
  const int lane = tid & 63;
  const int wid = tid >> 6;          // 0..7
  const int wm = wid >> 2;           // 0..1
  const int wn = wid & 3;            // 0..3
  const int c16 = lane & 15, quad = lane >> 4;

  // bijective XCD-chunk swizzle (handles nwg % 8 != 0)
  const int nwg = (int)gridDim.x;
  const int q = nwg >> 3, r = nwg & 7;
  const int xcd = blockIdx.x & 7, bidx = (int)blockIdx.x >> 3;
  const int vb = (xcd < r) ? xcd * (q + 1) + bidx : r + xcd * q + bidx;
  const int vtile = vb % VT_;
  const int mtile = vb / VT_;

  const int v0 = vtile * 256;
  const int prow0 = mtile * 256;
  const int m0 = mbase + prow0;

  const int l3 = lane >> 3;
  const int cA = (lane & 7) ^ l3;
  const int grA = (l3 << 1) + (cA >> 2);
  const int gcA = (cA & 3) << 3;
  const int rA0 = (wid & 4) * 32 + (wid & 3) * 16;
  const int rB0 = (wid >> 1) * 64 + (wid & 1) * 16;

  const bf16_t* gA = Xb + (size_t)(m0 + grA) * FP_ + gcA;
  const bf16_t* gB = Wt + (size_t)(v0 + grA) * FP_ + gcA;

  // bias loads issued BEFORE stages; prologue uses VMW(0) so in-loop counted
  // gates only ever see stage copies outstanding.
  float bv[4];
#pragma unroll
  for (int J = 0; J < 4; J++)
    bv[J] = bias[v0 + wn * 64 + (J >> 1) * 32 + (J & 1) * 16 + c16];

  f32x4 acc[8][4];
#pragma unroll
  for (int i = 0; i < 8; i++)
#pragma unroll
    for (int j = 0; j < 4; j++) acc[i][j] = (f32x4){0.f, 0.f, 0.f, 0.f};

  bf16x8 af[4][2], bfr[2][2];

#define G1_STAGE_A(buf, t, half)                                        \
  do {                                                                  \
    int r0_ = rA0 + (half) * 64;                                        \
    const bf16_t* s_ = gA + (size_t)r0_ * FP_ + (t) * 64;               \
    async_copy16(s_,      &smem[((buf) * 2 + 0) * 8192 + r0_ * 32]);    \
    async_copy16(s_ + 32, &smem[((buf) * 2 + 1) * 8192 + r0_ * 32]);    \
  } while (0)
#define G1_STAGE_B(buf, t, half)                                        \
  do {                                                                  \
    int r0_ = rB0 + (half) * 32;                                        \
    const bf16_t* s_ = gB + (size_t)r0_ * FP_ + (t) * 64;               \
    async_copy16(s_,      &smem[32768 + ((buf) * 2 + 0) * 8192 + r0_ * 32]); \
    async_copy16(s_ + 32, &smem[32768 + ((buf) * 2 + 1) * 8192 + r0_ * 32]); \
  } while (0)
#define G1_READ_A(buf, mh)                                              \
  do {                                                                  \
    _Pragma("unroll")                                                   \
    for (int i_ = 0; i_ < 4; i_++) {                                    \
      int r_ = wm * 128 + (mh) * 64 + i_ * 16 + c16;                    \
      int pa_ = r_ >> 1;                                                \
      int cz_ = ((((r_ & 1) << 2) | quad) ^ (pa_ & 7)) << 3;            \
      af[i_][0] = *(const bf16x8*)&smem[((buf) * 2 + 0) * 8192 + pa_ * 64 + cz_]; \
      af[i_][1] = *(const bf16x8*)&smem[((buf) * 2 + 1) * 8192 + pa_ * 64 + cz_]; \
    }                                                                   \
  } while (0)
#define G1_READ_B(buf, nh)                                              \
  do {                                                                  \
    _Pragma("unroll")                                                   \
    for (int j_ = 0; j_ < 2; j_++) {                                    \
      int r_ = wn * 64 + (nh) * 32 + j_ * 16 + c16;                     \
      int pn_ = r_ >> 1;                                                \
      int cz_ = ((((r_ & 1) << 2) | quad) ^ (pn_ & 7)) << 3;            \
      bfr[j_][0] = *(const bf16x8*)&smem[32768 + ((buf) * 2 + 0) * 8192 + pn_ * 64 + cz_]; \
      bfr[j_][1] = *(const bf16x8*)&smem[32768 + ((buf) * 2 + 1) * 8192 + pn_ * 64 + cz_]; \
    }                                                                   \
  } while (0)
#define G1_MFMA16(mh, nh)                                               \
  do {                                                                  \
    __builtin_amdgcn_s_setprio(1);                                      \
    _Pragma("unroll")                                                   \
    for (int i_ = 0; i_ < 4; i_++)                                      \
      _Pragma("unroll")                                                 \
      for (int j_ = 0; j_ < 2; j_++) {                                  \
        acc[(mh)*4 + i_][(nh)*2 + j_] = __builtin_amdgcn_mfma_f32_16x16x32_bf16( \
            af[i_][0], bfr[j_][0], acc[(mh)*4 + i_][(nh)*2 + j_], 0, 0, 0);      \
        acc[(mh)*4 + i_][(nh)*2 + j_] = __builtin_amdgcn_mfma_f32_16x16x32_bf16( \
            af[i_][1], bfr[j_][1], acc[(mh)*4 + i_][(nh)*2 + j_], 0, 0, 0);      \
      }                                                                 \
    __builtin_amdgcn_s_setprio(0);                                      \
  } while (0)

  // prologue: stage tile 0; full drain (bias loads also outstanding)
  G1_STAGE_A(0, 0, 0); G1_STAGE_B(0, 0, 0); G1_STAGE_B(0, 0, 1); G1_STAGE_A(0, 0, 1);
  VMW(0);
  BAR();

  const int NT = 4;   // FP_/64
#pragma unroll
  for (int t = 0; t < NT; ++t) {
    const int cur = t & 1, nb = cur ^ 1;
    const bool pf = (t + 1 < NT);

    // ---- p0 ----
    G1_READ_A(cur, 0); G1_READ_B(cur, 0);
    if (pf) G1_STAGE_A(nb, t + 1, 0);
    LGW(8);
    BAR();
    LGW(0);
    G1_MFMA16(0, 0);
    if (pf) VMW(4); else VMW(2);
    BAR();

    // ---- p1 ----
    G1_READ_B(cur, 1);
    if (pf) G1_STAGE_B(nb, t + 1, 0);
    BAR();
    LGW(0);
    G1_MFMA16(0, 1);
    if (pf) VMW(4); else VMW(0);
    BAR();

    // ---- p2 ----
    G1_READ_A(cur, 1);
    if (pf) G1_STAGE_B(nb, t + 1, 1);
    BAR();
    LGW(0);
    G1_MFMA16(1, 1);
    BAR();

    // ---- p3 ----
    G1_READ_B(cur, 0);
    if (pf) G1_STAGE_A(nb, t + 1, 1);
    BAR();
    LGW(0);
    G1_MFMA16(1, 0);
    if (pf) {
      VMW(4);
      BAR();
    }
  }

  // ---- epilogue pass 1 (registers only, overlaps other waves' tail MFMAs):
  // exp + bf16 round + per-row partial sum over THIS WAVE's 64 columns;
  // plain store to this wave's own rs_part slot (no atomics, no races).
#pragma unroll
  for (int I = 0; I < 8; I++) {
    int rowb = wm * 128 + (I >> 2) * 64 + (I & 3) * 16;
#pragma unroll
    for (int e = 0; e < 4; e++) {
      int row = rowb + quad * 4 + e;
      float s = 0.0f;
#pragma unroll
      for (int J = 0; J < 4; J++) {
        float p = __expf(acc[I][J][e] + bv[J]);
        float pf32 = (float)(bf16_t)p;   // value that will be stored in P
        acc[I][J][e] = pf32;
        s += pf32;
      }
#pragma unroll
      for (int off = 1; off < 16; off <<= 1) s += __shfl_xor(s, off, 16);
      if (c16 == 0)
        rs_part[(size_t)(prow0 + row) * 512 + vtile * 4 + wn] = s;
    }
  }

  // ---- epilogue pass 2: stage bf16 tile in LDS (row&7 XOR chunk swizzle) ----
  __syncthreads();   // all waves done reading K-loop LDS
#pragma unroll
  for (int I = 0; I < 8; I++) {
    int rowb = wm * 128 + (I >> 2) * 64 + (I & 3) * 16;
#pragma unroll
    for (int e = 0; e < 4; e++) {
      int row = rowb + quad * 4 + e;
#pragma unroll
      for (int J = 0; J < 4; J++) {
        int ch = wn * 8 + (J >> 1) * 4 + (J & 1) * 2 + (c16 >> 3);
        smem[row * 256 + ((ch ^ (row & 7)) << 3) + (c16 & 7)] = (bf16_t)acc[I][J][e];
      }
    }
  }
  __syncthreads();
  // coalesced b128 stores: 16 per thread, 512B contiguous per row-half
#pragma unroll
  for (int it = 0; it < 16; it++) {
    int idx2 = it * 512 + tid;
    int row = idx2 >> 5, ch = idx2 & 31;
    *(bf16x8*)&P[(size_t)(prow0 + row) * V_ + v0 + ch * 8] =
        *(const bf16x8*)&smem[row * 256 + ((ch ^ (row & 7)) << 3)];
  }
#undef G1_STAGE_A
#undef G1_STAGE_B
#undef G1_READ_A
#undef G1_READ_B
#undef G1_MFMA16
}

// -------- rowsum reduce: rowsum[mbase+row] = sum of 500 per-wave partials --------
__global__ void k_rowsum_reduce(const float* __restrict__ rs_part,
                                float* __restrict__ rowsum, int mbase) {
  int row = blockIdx.x * 4 + (threadIdx.x >> 6);
  int lane = threadIdx.x & 63;
  float s = 0.0f;
  for (int j = lane; j < VT_ * 4; j += 64) s += rs_part[(size_t)row * 512 + j];
#pragma unroll
  for (int off = 32; off >= 1; off >>= 1) s += __shfl_xor(s, off, 64);
  if (lane == 0) rowsum[mbase + row] = s;
}

// ======== GEMM2: 256x256 tile, BK=64, 8 waves, 2-buffer LDS, 4-phase counted
// vmcnt pipeline, setprio, XCD swizzle. (unchanged — proven) ========
__global__ __launch_bounds__(512, 2) void k_gemm2(
    const bf16_t* __restrict__ P, const bf16_t* __restrict__ Et,
    float* __restrict__ partial, int mtiles, int chunkrows, int kper) {
  __shared__ __align__(16) bf16_t ldsA[2][2][8192];
  __shared__ __align__(16) bf16_t ldsB[2][2][8192];

  const int tid = threadIdx.x;
  const int lane = tid & 63;
  const int wid = tid >> 6;
  const int wm = wid >> 2;
  const int wn = wid & 3;
  const int c16 = lane & 15, quad = lane >> 4;

  const int nwg = (int)gridDim.x;
  const int xcd = blockIdx.x & 7;
  const int vb = xcd * (nwg >> 3) + ((int)blockIdx.x >> 3);
  const int dtile = vb & 3;
  const int rest = vb >> 2;
  const int mtile = rest % mtiles;
  const int kslice = rest / mtiles;

  const int d0 = dtile * 256;
  const int prow0 = mtile * 256;
  const int kbase = kslice * kper;
  float* __restrict__ o = partial + (size_t)kslice * chunkrows * D_;

  const int l3 = lane >> 3;
  const int cA = (lane & 7) ^ l3;
  const int grA = (l3 << 1) + (cA >> 2);
  const int gcA = (cA & 3) << 3;

  const int rA0 = (wid & 4) * 32 + (wid & 3) * 16;
  const int rB0 = (wid >> 1) * 64 + (wid & 1) * 16;

  const bf16_t* gA = P  + (size_t)(prow0 + grA) * V_ + kbase + gcA;
  const bf16_t* gB = Et + (size_t)(d0   + grA) * V_ + kbase + gcA;

  f32x4 acc[8][4];
#pragma unroll
  for (int i = 0; i < 8; i++)
#pragma unroll
    for (int j = 0; j < 4; j++) acc[i][j] = (f32x4){0.f, 0.f, 0.f, 0.f};

  bf16x8 af[4][2], bfr[2][2];

#define STAGE_A(buf, t, half)                                          \
  do {                                                                 \
    int r0_ = rA0 + (half) * 64;                                       \
    const bf16_t* s_ = gA + (size_t)r0_ * V_ + (t) * 64;               \
    async_copy16(s_,      &ldsA[buf][0][r0_ * 32]);                    \
    async_copy16(s_ + 32, &ldsA[buf][1][r0_ * 32]);                    \
  } while (0)
#define STAGE_B(buf, t, half)                                          \
  do {                                                                 \
    int r0_ = rB0 + (half) * 32;                                       \
    const bf16_t* s_ = gB + (size_t)r0_ * V_ + (t) * 64;               \
    async_copy16(s_,      &ldsB[buf][0][r0_ * 32]);                    \
    async_copy16(s_ + 32, &ldsB[buf][1][r0_ * 32]);                    \
  } while (0)
#define READ_A(buf, mh)                                                \
  do {                                                                 \
    _Pragma("unroll")                                                  \
    for (int i_ = 0; i_ < 4; i_++) {                                   \
      int r_ = wm * 128 + (mh) * 64 + i_ * 16 + c16;                   \
      int pa_ = r_ >> 1;                                               \
      int cz_ = ((((r_ & 1) << 2) | quad) ^ (pa_ & 7)) << 3;           \
      af[i_][0] = *(const bf16x8*)&ldsA[buf][0][pa_ * 64 + cz_];       \
      af[i_][1] = *(const bf16x8*)&ldsA[buf][1][pa_ * 64 + cz_];       \
    }                                                                  \
  } while (0)
#define READ_B(buf, nh)                                                \
  do {                                                                 \
    _Pragma("unroll")                                                  \
    for (int j_ = 0; j_ < 2; j_++) {                                   \
      int r_ = wn * 64 + (nh) * 32 + j_ * 16 + c16;                    \
      int pn_ = r_ >> 1;                                               \
      int cz_ = ((((r_ & 1) << 2) | quad) ^ (pn_ & 7)) << 3;           \
      bfr[j_][0] = *(const bf16x8*)&ldsB[buf][0][pn_ * 64 + cz_];      \
      bfr[j_][1] = *(const bf16x8*)&ldsB[buf][1][pn_ * 64 + cz_];      \
    }                                                                  \
  } while (0)
#define MFMA16(mh, nh)                                                 \
  do {                                                                 \
    __builtin_amdgcn_s_setprio(1);                                     \
    _Pragma("unroll")                                                  \
    for (int i_ = 0; i_ < 4; i_++)                                     \
      _Pragma("unroll")                                                \
      for (int j_ = 0; j_ < 2; j_++) {                                 \
        acc[(mh)*4 + i_][(nh)*2 + j_] = __builtin_amdgcn_mfma_f32_16x16x32_bf16( \
            af[i_][0], bfr[j_][0], acc[(mh)*4 + i_][(nh)*2 + j_], 0, 0, 0);      \
        acc[(mh)*4 + i_][(nh)*2 + j_] = __builtin_amdgcn_mfma_f32_16x16x32_bf16( \
            af[i_][1], bfr[j_][1], acc[(mh)*4 + i_][(nh)*2 + j_], 0, 0, 0);      \
      }                                                                \
    __builtin_amdgcn_s_setprio(0);                                     \
  } while (0)

  STAGE_A(0, 0, 0); STAGE_B(0, 0, 0); STAGE_B(0, 0, 1); STAGE_A(0, 0, 1);
  VMW(4);
  BAR();

  const int NT = kper >> 6;
  for (int t = 0; t < NT; ++t) {
    const int cur = t & 1, nb = cur ^ 1;
    const bool pf = (t + 1 < NT);

    READ_A(cur, 0); READ_B(cur, 0);
    if (pf) STAGE_A(nb, t + 1, 0);
    LGW(8);
    BAR();
    LGW(0);
    MFMA16(0, 0);
    if (pf) VMW(4); else VMW(2);
    BAR();

    READ_B(cur, 1);
    if (pf) STAGE_B(nb, t + 1, 0);
    BAR();
    LGW(0);
    MFMA16(0, 1);
    if (pf) VMW(4); else VMW(0);
    BAR();

    READ_A(cur, 1);
    if (pf) STAGE_B(nb, t + 1, 1);
    BAR();
    LGW(0);
    MFMA16(1, 1);
    BAR();

    READ_B(cur, 0);
    if (pf) STAGE_A(nb, t + 1, 1);
    BAR();
    LGW(0);
    MFMA16(1, 0);
    if (pf) {
      VMW(4);
      BAR();
    }
  }

#pragma unroll
  for (int I = 0; I < 8; I++) {
    int rowb = wm * 128 + (I >> 2) * 64 + (I & 3) * 16;
#pragma unroll
    for (int e = 0; e < 4; e++) {
      int pr = prow0 + rowb + quad * 4 + e;
#pragma unroll
      for (int J = 0; J < 4; J++) {
        int d = d0 + wn * 64 + (J >> 1) * 32 + (J & 1) * 16 + c16;
        o[(size_t)pr * D_ + d] = acc[I][J][e];
      }
    }
  }
#undef STAGE_A
#undef STAGE_B
#undef READ_A
#undef READ_B
#undef MFMA16
}

#undef BAR
#undef VMW
#undef LGW

// -------- finalize: out[mbase+lr][:] = (sum_z partial[z]) / rowsum --------
__global__ void k_finalize(const float* __restrict__ partial,
                           const float* __restrict__ rowsum, float* __restrict__ out,
                           int mbase, int rows, int ks) {
  int i = blockIdx.x * 256 + threadIdx.x;   // over rows*D/4
  int lr = i >> 8;                          // /(D_/4)
  float inv = 1.0f / rowsum[mbase + lr];
  f32x4 s = (f32x4){0.f, 0.f, 0.f, 0.f};
  for (int z = 0; z < ks; z++) {
    f32x4 a = ((const f32x4*)(partial + (size_t)z * rows * D_))[i];
    s.x += a.x; s.y += a.y; s.z += a.z; s.w += a.w;
  }
  s.x *= inv; s.y *= inv; s.z *= inv; s.w *= inv;
  ((f32x4*)out)[(size_t)mbase * (D_ / 4) + i] = s;
}

// ======== host ========
extern "C" void kernel_launch(void* const* d_in, const int* in_sizes, int n_in,
                              void* d_out, int out_size, void* d_ws, size_t ws_size,
                              hipStream_t stream) {
  const float* xp   = (const float*)d_in[0];   // (B,N,FP,TP)
  const float* E    = (const float*)d_in[1];   // (V,D)
  const float* W    = (const float*)d_in[2];   // (FP,V)
  const float* bias = (const float*)d_in[3];   // (V)
  float* out = (float*)d_out;                  // (M,D)

  char* ws = (char*)d_ws;
  const size_t szXb = (size_t)M_ * FP_ * 2;
  const size_t szWt = (size_t)V_ * FP_ * 2;
  const size_t szEt = (size_t)D_ * V_ * 2;
  const size_t szRs = (size_t)M_ * 4;
  bf16_t* Xb = (bf16_t*)ws;
  bf16_t* Wt = (bf16_t*)(ws + szXb);
  bf16_t* Et = (bf16_t*)(ws + szXb + szWt);
  float* rowsum = (float*)(ws + szXb + szWt + szEt);
  const size_t fixed = szXb + szWt + szEt + szRs;

  // chunk from {8192,4096,2048,1024}; per-row cost: P (V*2) + partials (ks*D*4)
  // + rs_part (512*4)
  const int copt[4] = {8192, 4096, 2048, 1024};
  const int kopt[4] = {2, 4, 10, 20};
  int chunk = 1024, ksv = 20;
  size_t avail = (ws_size > fixed) ? ws_size - fixed : 0;
  for (int i = 0; i < 4; i++) {
    size_t need = (size_t)copt[i] * V_ * 2 + (size_t)kopt[i] * copt[i] * D_ * 4
                + (size_t)copt[i] * 512 * 4;
    if (need <= avail) { chunk = copt[i]; ksv = kopt[i]; break; }
  }
  bf16_t* P = (bf16_t*)(ws + fixed);
  float* partial = (float*)(ws + fixed + (size_t)chunk * V_ * 2);
  float* rs_part = (float*)(ws + fixed + (size_t)chunk * V_ * 2
                            + (size_t)ksv * chunk * D_ * 4);
  const int kper = V_ / ksv;

  k_convert_x<<<B_ * N_, 256, 0, stream>>>(xp, Xb);
  {
    dim3 g(V_ / 64, FP_ / 64);
    k_transpose_cvt<<<g, 256, 0, stream>>>(W, Wt, FP_, V_);
  }
  {
    dim3 g(D_ / 64, V_ / 64);
    k_transpose_cvt<<<g, 256, 0, stream>>>(E, Et, V_, D_);
  }

  for (int mb = 0; mb < M_; mb += chunk) {
    int rows = M_ - mb;
    if (rows > chunk) rows = chunk;          // always == chunk (M_ % chunk == 0)

    int nwg1 = VT_ * (rows / 256);
    k_gemm1<<<nwg1, 512, 0, stream>>>(Xb, Wt, bias, P, rs_part, mb);
    k_rowsum_reduce<<<rows / 4, 256, 0, stream>>>(rs_part, rowsum, mb);

    int mt = rows / 256;
    int nwg2 = 4 * mt * ksv;
    k_gemm2<<<nwg2, 512, 0, stream>>>(P, Et, partial, mt, rows, kper);

    k_finalize<<<rows, 256, 0, stream>>>(partial, rowsum, out, mb, rows, ksv);
  }
}